// Round 1
// baseline (1965.734 us; speedup 1.0000x reference)
//
#include <hip/hip_runtime.h>
#include <hip/hip_bf16.h>
#include <math.h>

#define EMBED 1024
#define KD 64
#define NH 16
#define SEQ 2048
#define BATCH 4

typedef float4 f4;

// ------------------------------------------------------------------
// Kernel 1: fused QKV projection.
// Logical GEMM: [M=8192, D=1024] x [D=1024, N=3072] where N splits into
// Q (0..1023), K (1024..2047), V (2048..3071); col-within-matrix = h*64+c,
// weight element W[d][h*64+c] = wsrc[h][d][c]  (wsrc is [H, D, K] row-major).
// 128x128 tile, BK=16, 256 threads, 8x8 accum per thread.
// Output layout: Q/K/V as [B, H, S, 64] fp32 (attention-friendly).
// ------------------------------------------------------------------
__global__ __launch_bounds__(256)
void qkv_proj_kernel(const float* __restrict__ x,
                     const float* __restrict__ wq,
                     const float* __restrict__ wk,
                     const float* __restrict__ wv,
                     float* __restrict__ Qm,
                     float* __restrict__ Km,
                     float* __restrict__ Vm)
{
    __shared__ float As[16][132];   // [k][m], pad 132 so transposed writes spread banks
    __shared__ float Bs[16][128];   // [k][n]
    const int tid = threadIdx.x;
    const int tx = tid & 15, ty = tid >> 4;
    const int row0 = blockIdx.x * 128;
    const int n0 = blockIdx.y * 128;          // 0..3071
    const int mat = n0 >> 10;                 // 0=Q 1=K 2=V
    const int nin = n0 & 1023;                // within-matrix col base (mult of 128)
    const float* __restrict__ wsrc = (mat == 0) ? wq : (mat == 1) ? wk : wv;
    float* __restrict__ dst = (mat == 0) ? Qm : (mat == 1) ? Km : Vm;

    float acc[8][8];
#pragma unroll
    for (int i = 0; i < 8; ++i)
#pragma unroll
        for (int j = 0; j < 8; ++j) acc[i][j] = 0.f;

    for (int d0 = 0; d0 < EMBED; d0 += 16) {
        __syncthreads();
        // ---- stage x tile: 128 rows x 16 d  (512 float4)
#pragma unroll
        for (int it = 0; it < 2; ++it) {
            int l = tid + it * 256;           // float4 index
            int r = l >> 2;                   // 0..127
            int c4 = (l & 3) << 2;            // 0,4,8,12
            f4 v = *(const f4*)(x + (size_t)(row0 + r) * EMBED + d0 + c4);
            As[c4 + 0][r] = v.x;
            As[c4 + 1][r] = v.y;
            As[c4 + 2][r] = v.z;
            As[c4 + 3][r] = v.w;
        }
        // ---- stage weight tile: 16 d x 128 n  (512 float4)
#pragma unroll
        for (int it = 0; it < 2; ++it) {
            int l = tid + it * 256;
            int k = l >> 5;                   // 0..15
            int nn = (l & 31) << 2;           // 0..124
            int n = nin + nn;
            int h = n >> 6, cc = n & 63;      // cc multiple of 4, +3 stays in head
            f4 v = *(const f4*)(wsrc + ((size_t)h * EMBED + (d0 + k)) * KD + cc);
            *(f4*)&Bs[k][nn] = v;
        }
        __syncthreads();
#pragma unroll
        for (int k = 0; k < 16; ++k) {
            float a[8], b[8];
            *(f4*)&a[0] = *(f4*)&As[k][ty * 8];
            *(f4*)&a[4] = *(f4*)&As[k][ty * 8 + 4];
            // split cols {tx*4.., 64+tx*4..} -> conflict-free b128 LDS reads
            *(f4*)&b[0] = *(f4*)&Bs[k][tx * 4];
            *(f4*)&b[4] = *(f4*)&Bs[k][64 + tx * 4];
#pragma unroll
            for (int i = 0; i < 8; ++i)
#pragma unroll
                for (int j = 0; j < 8; ++j)
                    acc[i][j] = fmaf(a[i], b[j], acc[i][j]);
        }
    }
    // ---- epilogue: write [B,H,S,64]
#pragma unroll
    for (int i = 0; i < 8; ++i) {
        int row = row0 + ty * 8 + i;
        int bb = row >> 11, s = row & 2047;
#pragma unroll
        for (int g = 0; g < 2; ++g) {
            int n = nin + g * 64 + tx * 4;
            int h = n >> 6, cc = n & 63;
            f4 o;
            o.x = acc[i][g * 4 + 0];
            o.y = acc[i][g * 4 + 1];
            o.z = acc[i][g * 4 + 2];
            o.w = acc[i][g * 4 + 3];
            *(f4*)(dst + (((size_t)bb * NH + h) * SEQ + s) * KD + cc) = o;
        }
    }
}

// ------------------------------------------------------------------
// Kernel 2: flash attention, fp32.
// Block = 256 threads handles one (b,h) x 64-row Q tile; loops over 32
// 64-key tiles with online softmax. K is stored transposed in LDS so the
// score inner loop reads both operands conflict-free. Row state (m,l) is
// replicated across the 16 lanes of each row-group (identical arithmetic
// after __shfl_xor reductions).
// ------------------------------------------------------------------
#define RANK4(i, ai)                                                     \
    s[i][0] += ai.x * b0.x + ai.y * b1.x + ai.z * b2.x + ai.w * b3.x;    \
    s[i][1] += ai.x * b0.y + ai.y * b1.y + ai.z * b2.y + ai.w * b3.y;    \
    s[i][2] += ai.x * b0.z + ai.y * b1.z + ai.z * b2.z + ai.w * b3.z;    \
    s[i][3] += ai.x * b0.w + ai.y * b1.w + ai.z * b2.w + ai.w * b3.w;

#define PVACC(i, pi)                                                     \
    ctx[i][0] += pi.x * v0.x + pi.y * v1.x + pi.z * v2.x + pi.w * v3.x;  \
    ctx[i][1] += pi.x * v0.y + pi.y * v1.y + pi.z * v2.y + pi.w * v3.y;  \
    ctx[i][2] += pi.x * v0.z + pi.y * v1.z + pi.z * v2.z + pi.w * v3.z;  \
    ctx[i][3] += pi.x * v0.w + pi.y * v1.w + pi.z * v2.w + pi.w * v3.w;

__global__ __launch_bounds__(256)
void attn_kernel(const float* __restrict__ Qm,
                 const float* __restrict__ Km,
                 const float* __restrict__ Vm,
                 float* __restrict__ heads)
{
    __shared__ float Qs[64][68];    // [qrow][c]
    __shared__ float KsT[64][68];   // [c][t]  (transposed)
    __shared__ float Vs[64][68];    // [t][c]
    __shared__ float Ps[64][68];    // [qrow][t]
    const int tid = threadIdx.x;
    const int tx = tid & 15, ty = tid >> 4;
    const int bh = blockIdx.y;                  // b*16+h
    const int q0 = blockIdx.x * 64;
    const float* __restrict__ Qb = Qm + (size_t)bh * SEQ * KD;
    const float* __restrict__ Kb = Km + (size_t)bh * SEQ * KD;
    const float* __restrict__ Vb = Vm + (size_t)bh * SEQ * KD;

    // load Q tile (64x64)
#pragma unroll
    for (int it = 0; it < 4; ++it) {
        int l = tid + it * 256;
        int r = l >> 4, c = (l & 15) << 2;
        *(f4*)&Qs[r][c] = *(const f4*)(Qb + (size_t)(q0 + r) * KD + c);
    }

    float m_run[4], l_run[4], ctx[4][4];
#pragma unroll
    for (int i = 0; i < 4; ++i) {
        m_run[i] = -INFINITY;
        l_run[i] = 0.f;
#pragma unroll
        for (int j = 0; j < 4; ++j) ctx[i][j] = 0.f;
    }
    __syncthreads();

    for (int t0 = 0; t0 < SEQ; t0 += 64) {
        // stage K (transposed) and V tiles
#pragma unroll
        for (int it = 0; it < 4; ++it) {
            int l = tid + it * 256;
            int r = l >> 4, c = (l & 15) << 2;
            f4 kv = *(const f4*)(Kb + (size_t)(t0 + r) * KD + c);
            KsT[c + 0][r] = kv.x;
            KsT[c + 1][r] = kv.y;
            KsT[c + 2][r] = kv.z;
            KsT[c + 3][r] = kv.w;
            *(f4*)&Vs[r][c] = *(const f4*)(Vb + (size_t)(t0 + r) * KD + c);
        }
        __syncthreads();

        // scores: s[i][j] = sum_c Qs[ty*4+i][c] * KsT[c][tx*4+j]
        float s[4][4];
#pragma unroll
        for (int i = 0; i < 4; ++i)
#pragma unroll
            for (int j = 0; j < 4; ++j) s[i][j] = 0.f;
#pragma unroll 4
        for (int c = 0; c < 64; c += 4) {
            f4 a0 = *(f4*)&Qs[ty * 4 + 0][c];
            f4 a1 = *(f4*)&Qs[ty * 4 + 1][c];
            f4 a2 = *(f4*)&Qs[ty * 4 + 2][c];
            f4 a3 = *(f4*)&Qs[ty * 4 + 3][c];
            f4 b0 = *(f4*)&KsT[c + 0][tx * 4];
            f4 b1 = *(f4*)&KsT[c + 1][tx * 4];
            f4 b2 = *(f4*)&KsT[c + 2][tx * 4];
            f4 b3 = *(f4*)&KsT[c + 3][tx * 4];
            RANK4(0, a0)
            RANK4(1, a1)
            RANK4(2, a2)
            RANK4(3, a3)
        }

        // online softmax (scale 1/sqrt(64) = 0.125)
#pragma unroll
        for (int i = 0; i < 4; ++i) {
#pragma unroll
            for (int j = 0; j < 4; ++j) s[i][j] *= 0.125f;
            float mx = fmaxf(fmaxf(s[i][0], s[i][1]), fmaxf(s[i][2], s[i][3]));
            mx = fmaxf(mx, __shfl_xor(mx, 1));
            mx = fmaxf(mx, __shfl_xor(mx, 2));
            mx = fmaxf(mx, __shfl_xor(mx, 4));
            mx = fmaxf(mx, __shfl_xor(mx, 8));
            float mnew = fmaxf(m_run[i], mx);
            float alpha = __expf(m_run[i] - mnew);
            float rs = 0.f;
#pragma unroll
            for (int j = 0; j < 4; ++j) {
                float p = __expf(s[i][j] - mnew);
                s[i][j] = p;
                rs += p;
            }
            rs += __shfl_xor(rs, 1);
            rs += __shfl_xor(rs, 2);
            rs += __shfl_xor(rs, 4);
            rs += __shfl_xor(rs, 8);
            m_run[i] = mnew;
            l_run[i] = l_run[i] * alpha + rs;
#pragma unroll
            for (int j = 0; j < 4; ++j) ctx[i][j] *= alpha;
            f4 po;
            po.x = s[i][0]; po.y = s[i][1]; po.z = s[i][2]; po.w = s[i][3];
            *(f4*)&Ps[ty * 4 + i][tx * 4] = po;
        }
        __syncthreads();

        // ctx += P @ V : ctx[i][j] += sum_t Ps[ty*4+i][t] * Vs[t][tx*4+j]
#pragma unroll 4
        for (int t = 0; t < 64; t += 4) {
            f4 p0 = *(f4*)&Ps[ty * 4 + 0][t];
            f4 p1 = *(f4*)&Ps[ty * 4 + 1][t];
            f4 p2 = *(f4*)&Ps[ty * 4 + 2][t];
            f4 p3 = *(f4*)&Ps[ty * 4 + 3][t];
            f4 v0 = *(f4*)&Vs[t + 0][tx * 4];
            f4 v1 = *(f4*)&Vs[t + 1][tx * 4];
            f4 v2 = *(f4*)&Vs[t + 2][tx * 4];
            f4 v3 = *(f4*)&Vs[t + 3][tx * 4];
            PVACC(0, p0)
            PVACC(1, p1)
            PVACC(2, p2)
            PVACC(3, p3)
        }
        __syncthreads();
    }

    // epilogue: heads[b][s][h*64+c] = ctx / l
    const int bb = bh >> 4, h = bh & 15;
#pragma unroll
    for (int i = 0; i < 4; ++i) {
        int srow = q0 + ty * 4 + i;
        float inv = 1.0f / l_run[i];
        f4 o;
        o.x = ctx[i][0] * inv;
        o.y = ctx[i][1] * inv;
        o.z = ctx[i][2] * inv;
        o.w = ctx[i][3] * inv;
        *(f4*)(heads + ((size_t)bb * SEQ + srow) * EMBED + h * 64 + tx * 4) = o;
    }
}

// ------------------------------------------------------------------
// Kernel 3: output projection  out = heads[8192,1024] @ w[1024,1024]
// Same 128x128x16 sgemm structure as kernel 1.
// ------------------------------------------------------------------
__global__ __launch_bounds__(256)
void out_proj_kernel(const float* __restrict__ heads,
                     const float* __restrict__ w,
                     float* __restrict__ out)
{
    __shared__ float As[16][132];
    __shared__ float Bs[16][128];
    const int tid = threadIdx.x;
    const int tx = tid & 15, ty = tid >> 4;
    const int row0 = blockIdx.x * 128;
    const int n0 = blockIdx.y * 128;

    float acc[8][8];
#pragma unroll
    for (int i = 0; i < 8; ++i)
#pragma unroll
        for (int j = 0; j < 8; ++j) acc[i][j] = 0.f;

    for (int d0 = 0; d0 < EMBED; d0 += 16) {
        __syncthreads();
#pragma unroll
        for (int it = 0; it < 2; ++it) {
            int l = tid + it * 256;
            int r = l >> 2;
            int c4 = (l & 3) << 2;
            f4 v = *(const f4*)(heads + (size_t)(row0 + r) * EMBED + d0 + c4);
            As[c4 + 0][r] = v.x;
            As[c4 + 1][r] = v.y;
            As[c4 + 2][r] = v.z;
            As[c4 + 3][r] = v.w;
        }
#pragma unroll
        for (int it = 0; it < 2; ++it) {
            int l = tid + it * 256;
            int k = l >> 5;
            int nn = (l & 31) << 2;
            *(f4*)&Bs[k][nn] = *(const f4*)(w + (size_t)(d0 + k) * EMBED + n0 + nn);
        }
        __syncthreads();
#pragma unroll
        for (int k = 0; k < 16; ++k) {
            float a[8], b[8];
            *(f4*)&a[0] = *(f4*)&As[k][ty * 8];
            *(f4*)&a[4] = *(f4*)&As[k][ty * 8 + 4];
            *(f4*)&b[0] = *(f4*)&Bs[k][tx * 4];
            *(f4*)&b[4] = *(f4*)&Bs[k][64 + tx * 4];
#pragma unroll
            for (int i = 0; i < 8; ++i)
#pragma unroll
                for (int j = 0; j < 8; ++j)
                    acc[i][j] = fmaf(a[i], b[j], acc[i][j]);
        }
    }
#pragma unroll
    for (int i = 0; i < 8; ++i) {
        int row = row0 + ty * 8 + i;
#pragma unroll
        for (int g = 0; g < 2; ++g) {
            int n = n0 + g * 64 + tx * 4;
            f4 o;
            o.x = acc[i][g * 4 + 0];
            o.y = acc[i][g * 4 + 1];
            o.z = acc[i][g * 4 + 2];
            o.w = acc[i][g * 4 + 3];
            *(f4*)(out + (size_t)row * EMBED + n) = o;
        }
    }
}

// ------------------------------------------------------------------
extern "C" void kernel_launch(void* const* d_in, const int* in_sizes, int n_in,
                              void* d_out, int out_size, void* d_ws, size_t ws_size,
                              hipStream_t stream) {
    const float* x  = (const float*)d_in[0];
    const float* wq = (const float*)d_in[1];
    const float* wk = (const float*)d_in[2];
    const float* wv = (const float*)d_in[3];
    const float* w  = (const float*)d_in[4];
    float* out = (float*)d_out;

    const size_t perTensor = (size_t)BATCH * NH * SEQ * KD;   // 8,388,608 floats
    float* Qm = (float*)d_ws;
    float* Km = Qm + perTensor;
    float* Vm = Km + perTensor;
    float* heads = Vm + perTensor;                            // [B,S,1024]

    dim3 g1(64, 24);   // M/128 x 3072/128
    qkv_proj_kernel<<<g1, 256, 0, stream>>>(x, wq, wk, wv, Qm, Km, Vm);

    dim3 g2(SEQ / 64, BATCH * NH);   // 32 x 64
    attn_kernel<<<g2, 256, 0, stream>>>(Qm, Km, Vm, heads);

    dim3 g3(64, 8);    // M/128 x 1024/128
    out_proj_kernel<<<g3, 256, 0, stream>>>(heads, w, out);
}

// Round 2
// 1115.788 us; speedup vs baseline: 1.7617x; 1.7617x over previous
//
#include <hip/hip_runtime.h>
#include <hip/hip_bf16.h>
#include <math.h>

#define EMBED 1024
#define KD 64
#define NH 16
#define SEQ 2048
#define BATCH 4
#define BH (BATCH * NH)     // 64
#define NTOK ((size_t)BH * SEQ * KD)   // 8,388,608 elements per q/k/v tensor

typedef float4 f4;
typedef unsigned short u16;
typedef __attribute__((ext_vector_type(8))) short v8s;   // 8 bf16 = 4 VGPRs (MFMA A/B frag)
typedef __attribute__((ext_vector_type(4))) float v4f;   // MFMA C/D frag

// round-to-nearest-even fp32 -> bf16 bits
__device__ __forceinline__ u16 f2bf(float f) {
    unsigned u = __float_as_uint(f);
    unsigned r = (u + 0x7fffu + ((u >> 16) & 1u)) >> 16;
    return (u16)r;
}
__device__ __forceinline__ float bf2f(u16 h) {
    return __uint_as_float(((unsigned)h) << 16);
}

// async global->LDS, 16B per lane. LDS dest = wave-uniform base + lane*16;
// global src must include lane*16 explicitly.
__device__ __forceinline__ void gload_lds16(const void* g, void* l) {
    __builtin_amdgcn_global_load_lds(
        (const __attribute__((address_space(1))) unsigned int*)g,
        (__attribute__((address_space(3))) unsigned int*)l, 16, 0, 0);
}

// ------------------------------------------------------------------
// Kernel 1: fused QKV projection (fp32 main loop, same as R1).
// New epilogue:
//   Q -> Qhi/Qlo bf16 [bh][s][64], pre-scaled by 0.125 (exact)
//   K -> Khi/Klo bf16 [bh][s][64], hd-block XOR-swizzled: blk' = blk ^ (s&7)
//   V -> Vt bf16 [bh][hd][2048], key-block XOR-swizzled: kb' = kb ^ (hd&7)
// ------------------------------------------------------------------
__global__ __launch_bounds__(256)
void qkv_proj_kernel(const float* __restrict__ x,
                     const float* __restrict__ wq,
                     const float* __restrict__ wk,
                     const float* __restrict__ wv,
                     u16* __restrict__ Qhi, u16* __restrict__ Qlo,
                     u16* __restrict__ Khi, u16* __restrict__ Klo,
                     u16* __restrict__ Vt)
{
    __shared__ float As[16][132];
    __shared__ float Bs[16][128];
    const int tid = threadIdx.x;
    const int tx = tid & 15, ty = tid >> 4;
    const int row0 = blockIdx.x * 128;
    const int n0 = blockIdx.y * 128;          // 0..3071
    const int mat = n0 >> 10;                 // 0=Q 1=K 2=V
    const int nin = n0 & 1023;
    const float* __restrict__ wsrc = (mat == 0) ? wq : (mat == 1) ? wk : wv;

    float acc[8][8];
#pragma unroll
    for (int i = 0; i < 8; ++i)
#pragma unroll
        for (int j = 0; j < 8; ++j) acc[i][j] = 0.f;

    for (int d0 = 0; d0 < EMBED; d0 += 16) {
        __syncthreads();
#pragma unroll
        for (int it = 0; it < 2; ++it) {
            int l = tid + it * 256;
            int r = l >> 2;
            int c4 = (l & 3) << 2;
            f4 v = *(const f4*)(x + (size_t)(row0 + r) * EMBED + d0 + c4);
            As[c4 + 0][r] = v.x;
            As[c4 + 1][r] = v.y;
            As[c4 + 2][r] = v.z;
            As[c4 + 3][r] = v.w;
        }
#pragma unroll
        for (int it = 0; it < 2; ++it) {
            int l = tid + it * 256;
            int k = l >> 5;
            int nn = (l & 31) << 2;
            int n = nin + nn;
            int h = n >> 6, cc = n & 63;
            f4 v = *(const f4*)(wsrc + ((size_t)h * EMBED + (d0 + k)) * KD + cc);
            *(f4*)&Bs[k][nn] = v;
        }
        __syncthreads();
#pragma unroll
        for (int k = 0; k < 16; ++k) {
            float a[8], b[8];
            *(f4*)&a[0] = *(f4*)&As[k][ty * 8];
            *(f4*)&a[4] = *(f4*)&As[k][ty * 8 + 4];
            *(f4*)&b[0] = *(f4*)&Bs[k][tx * 4];
            *(f4*)&b[4] = *(f4*)&Bs[k][64 + tx * 4];
#pragma unroll
            for (int i = 0; i < 8; ++i)
#pragma unroll
                for (int j = 0; j < 8; ++j)
                    acc[i][j] = fmaf(a[i], b[j], acc[i][j]);
        }
    }

    // ---- epilogue ----
    if (mat == 2) {
        // V -> Vt[bh][hd][key], key-block swizzle kb^(hd&7), scalar bf16 stores
#pragma unroll
        for (int i = 0; i < 8; ++i) {
            int row = row0 + ty * 8 + i;
            int bb = row >> 11, s = row & 2047;
#pragma unroll
            for (int g = 0; g < 2; ++g) {
                int n = nin + g * 64 + tx * 4;
                int h = n >> 6, cc = n & 63;
                int bh = bb * NH + h;
#pragma unroll
                for (int j = 0; j < 4; ++j) {
                    int hd = cc + j;
                    size_t a = ((size_t)bh * KD + hd) * SEQ
                             + (size_t)((((s >> 3) ^ (hd & 7)) << 3) | (s & 7));
                    Vt[a] = f2bf(acc[i][g * 4 + j]);
                }
            }
        }
    } else {
        u16* __restrict__ dhi = (mat == 0) ? Qhi : Khi;
        u16* __restrict__ dlo = (mat == 0) ? Qlo : Klo;
        const float sc = (mat == 0) ? 0.125f : 1.0f;
#pragma unroll
        for (int i = 0; i < 8; ++i) {
            int row = row0 + ty * 8 + i;
            int bb = row >> 11, s = row & 2047;
#pragma unroll
            for (int g = 0; g < 2; ++g) {
                int n = nin + g * 64 + tx * 4;
                int h = n >> 6, cc = n & 63;
                int bh = bb * NH + h;
                int ccp = (mat == 0) ? cc : ((((cc >> 3) ^ (s & 7)) << 3) | (cc & 7));
                size_t base = ((size_t)bh * SEQ + s) * KD + ccp;
                unsigned hbits[4], lbits[4];
#pragma unroll
                for (int j = 0; j < 4; ++j) {
                    float f = acc[i][g * 4 + j] * sc;
                    u16 h16 = f2bf(f);
                    hbits[j] = h16;
                    lbits[j] = f2bf(f - bf2f(h16));
                }
                uint2 uh, ul;
                uh.x = hbits[0] | (hbits[1] << 16);
                uh.y = hbits[2] | (hbits[3] << 16);
                ul.x = lbits[0] | (lbits[1] << 16);
                ul.y = lbits[2] | (lbits[3] << 16);
                *(uint2*)(dhi + base) = uh;
                *(uint2*)(dlo + base) = ul;
            }
        }
    }
}

// ------------------------------------------------------------------
// Kernel 2: flash attention, MFMA 16x16x32 bf16, split-hi/lo QK^T.
// Block = 256 threads = 4 waves; 128 q-rows/block (32 per wave); 64-key
// tiles; Q frags resident in registers across all 32 KV iterations.
// ------------------------------------------------------------------
#define PSTRIDE 88   // ushorts; 176B row stride: 16B-aligned, conflict-checked

__global__ __launch_bounds__(256)
void attn_kernel(const u16* __restrict__ Qhi, const u16* __restrict__ Qlo,
                 const u16* __restrict__ Khi, const u16* __restrict__ Klo,
                 const u16* __restrict__ Vt,  float* __restrict__ heads)
{
    __shared__ u16 sKhi[64 * 64];
    __shared__ u16 sKlo[64 * 64];
    __shared__ u16 sVt[64 * 64];
    __shared__ u16 sPs[128 * PSTRIDE];

    const int tid = threadIdx.x;
    const int lane = tid & 63, wid = tid >> 6;
    const int lm = lane & 15, lq = lane >> 4;
    const int q0 = blockIdx.x * 128;
    const int bh = blockIdx.y;
    const int bb = bh >> 4, h = bh & 15;

    // ---- Q fragments in registers: rows wid*32+mt*16+lm, k = kk*32+lq*8..
    v8s qh[2][2], ql[2][2];
#pragma unroll
    for (int mt = 0; mt < 2; ++mt)
#pragma unroll
        for (int kk = 0; kk < 2; ++kk) {
            size_t g = ((size_t)bh * SEQ + q0 + wid * 32 + mt * 16 + lm) * KD
                     + kk * 32 + lq * 8;
            qh[mt][kk] = *(const v8s*)(Qhi + g);
            ql[mt][kk] = *(const v8s*)(Qlo + g);
        }

    v4f ctx[2][4];
    float mrun[2][4], lrun[2][4];
#pragma unroll
    for (int mt = 0; mt < 2; ++mt)
#pragma unroll
        for (int r = 0; r < 4; ++r) {
            mrun[mt][r] = -INFINITY;
            lrun[mt][r] = 0.f;
        }
#pragma unroll
    for (int mt = 0; mt < 2; ++mt)
#pragma unroll
        for (int nt = 0; nt < 4; ++nt)
            ctx[mt][nt] = (v4f){0.f, 0.f, 0.f, 0.f};

    const size_t kbase = (size_t)bh * SEQ * KD;     // ushort index

    for (int t0 = 0; t0 < SEQ; t0 += 64) {
        __syncthreads();    // previous iteration's LDS reads complete

        // ---- stage Khi/Klo tiles (8KB each, contiguous) via global_load_lds
        {
            const char* gk1 = (const char*)(Khi + kbase + (size_t)t0 * KD);
            const char* gk2 = (const char*)(Klo + kbase + (size_t)t0 * KD);
            char* l1 = (char*)sKhi;
            char* l2 = (char*)sKlo;
            int off = wid * 2048;
#pragma unroll
            for (int i = 0; i < 2; ++i) {
                int o = off + i * 1024;
                gload_lds16(gk1 + o + lane * 16, l1 + o);
                gload_lds16(gk2 + o + lane * 16, l2 + o);
            }
        }
        // ---- stage Vt tile: 64 rows(hd) x 128B (rows not contiguous in global)
#pragma unroll
        for (int it = 0; it < 2; ++it) {
            int slot = it * 256 + tid;        // 0..511
            int row = slot >> 3, seg = slot & 7;
            uint4 v = *(const uint4*)(Vt + ((size_t)(bh * KD + row)) * SEQ + t0 + seg * 8);
            *(uint4*)&sVt[row * 64 + seg * 8] = v;
        }
        asm volatile("s_waitcnt vmcnt(0)" ::: "memory");
        __syncthreads();

        // ---- QK^T: sc = Qhi*Khi + Qhi*Klo + Qlo*Khi  (fp32 accum)
        v4f sc[2][4];
#pragma unroll
        for (int mt = 0; mt < 2; ++mt)
#pragma unroll
            for (int nt = 0; nt < 4; ++nt)
                sc[mt][nt] = (v4f){0.f, 0.f, 0.f, 0.f};
#pragma unroll
        for (int kk = 0; kk < 2; ++kk) {
#pragma unroll
            for (int nt = 0; nt < 4; ++nt) {
                int key = nt * 16 + lm;
                int blk = (kk * 4 + lq) ^ (key & 7);   // hd-block swizzle
                v8s bh16 = *(const v8s*)&sKhi[key * 64 + blk * 8];
                v8s bl16 = *(const v8s*)&sKlo[key * 64 + blk * 8];
#pragma unroll
                for (int mt = 0; mt < 2; ++mt) {
                    sc[mt][nt] = __builtin_amdgcn_mfma_f32_16x16x32_bf16(qh[mt][kk], bh16, sc[mt][nt], 0, 0, 0);
                    sc[mt][nt] = __builtin_amdgcn_mfma_f32_16x16x32_bf16(qh[mt][kk], bl16, sc[mt][nt], 0, 0, 0);
                    sc[mt][nt] = __builtin_amdgcn_mfma_f32_16x16x32_bf16(ql[mt][kk], bh16, sc[mt][nt], 0, 0, 0);
                }
            }
        }

        // ---- online softmax. C-layout: col = nt*16+lm, row = mt*16+lq*4+r.
#pragma unroll
        for (int mt = 0; mt < 2; ++mt) {
#pragma unroll
            for (int r = 0; r < 4; ++r) {
                float v0 = sc[mt][0][r], v1 = sc[mt][1][r];
                float v2 = sc[mt][2][r], v3 = sc[mt][3][r];
                float mx = fmaxf(fmaxf(v0, v1), fmaxf(v2, v3));
                mx = fmaxf(mx, __shfl_xor(mx, 1));
                mx = fmaxf(mx, __shfl_xor(mx, 2));
                mx = fmaxf(mx, __shfl_xor(mx, 4));
                mx = fmaxf(mx, __shfl_xor(mx, 8));
                float mnew = fmaxf(mrun[mt][r], mx);
                float alpha = __expf(mrun[mt][r] - mnew);
                float p0 = __expf(v0 - mnew), p1 = __expf(v1 - mnew);
                float p2 = __expf(v2 - mnew), p3 = __expf(v3 - mnew);
                float rs = p0 + p1 + p2 + p3;
                rs += __shfl_xor(rs, 1);
                rs += __shfl_xor(rs, 2);
                rs += __shfl_xor(rs, 4);
                rs += __shfl_xor(rs, 8);
                mrun[mt][r] = mnew;
                lrun[mt][r] = lrun[mt][r] * alpha + rs;
#pragma unroll
                for (int nt = 0; nt < 4; ++nt) {
                    ctx[mt][nt][r] *= alpha;
                }
                int row = wid * 32 + mt * 16 + lq * 4 + r;
                sPs[row * PSTRIDE +  0 + lm] = f2bf(p0);
                sPs[row * PSTRIDE + 16 + lm] = f2bf(p1);
                sPs[row * PSTRIDE + 32 + lm] = f2bf(p2);
                sPs[row * PSTRIDE + 48 + lm] = f2bf(p3);
            }
        }
        // (same-wave ds_write -> ds_read; compiler inserts lgkmcnt wait)

        // ---- PV: ctx += P @ V
#pragma unroll
        for (int kk2 = 0; kk2 < 2; ++kk2) {
            v8s a[2];
#pragma unroll
            for (int mt = 0; mt < 2; ++mt)
                a[mt] = *(const v8s*)&sPs[(wid * 32 + mt * 16 + lm) * PSTRIDE + kk2 * 32 + lq * 8];
#pragma unroll
            for (int nt = 0; nt < 4; ++nt) {
                int hd = nt * 16 + lm;
                int blk = (kk2 * 4 + lq) ^ (hd & 7);   // key-block swizzle
                v8s b = *(const v8s*)&sVt[hd * 64 + blk * 8];
#pragma unroll
                for (int mt = 0; mt < 2; ++mt)
                    ctx[mt][nt] = __builtin_amdgcn_mfma_f32_16x16x32_bf16(a[mt], b, ctx[mt][nt], 0, 0, 0);
            }
        }
    }

    // ---- epilogue: heads[bb][row][h*64+hd] = ctx / l
#pragma unroll
    for (int mt = 0; mt < 2; ++mt)
#pragma unroll
        for (int r = 0; r < 4; ++r) {
            int row = q0 + wid * 32 + mt * 16 + lq * 4 + r;
            float inv = 1.0f / lrun[mt][r];
            float* dst = heads + ((size_t)bb * SEQ + row) * EMBED + h * KD;
#pragma unroll
            for (int nt = 0; nt < 4; ++nt)
                dst[nt * 16 + lm] = ctx[mt][nt][r] * inv;
        }
}

// ------------------------------------------------------------------
// Kernel 3: output projection  out = heads[8192,1024] @ w[1024,1024]
// (unchanged fp32 sgemm)
// ------------------------------------------------------------------
__global__ __launch_bounds__(256)
void out_proj_kernel(const float* __restrict__ heads,
                     const float* __restrict__ w,
                     float* __restrict__ out)
{
    __shared__ float As[16][132];
    __shared__ float Bs[16][128];
    const int tid = threadIdx.x;
    const int tx = tid & 15, ty = tid >> 4;
    const int row0 = blockIdx.x * 128;
    const int n0 = blockIdx.y * 128;

    float acc[8][8];
#pragma unroll
    for (int i = 0; i < 8; ++i)
#pragma unroll
        for (int j = 0; j < 8; ++j) acc[i][j] = 0.f;

    for (int d0 = 0; d0 < EMBED; d0 += 16) {
        __syncthreads();
#pragma unroll
        for (int it = 0; it < 2; ++it) {
            int l = tid + it * 256;
            int r = l >> 2;
            int c4 = (l & 3) << 2;
            f4 v = *(const f4*)(heads + (size_t)(row0 + r) * EMBED + d0 + c4);
            As[c4 + 0][r] = v.x;
            As[c4 + 1][r] = v.y;
            As[c4 + 2][r] = v.z;
            As[c4 + 3][r] = v.w;
        }
#pragma unroll
        for (int it = 0; it < 2; ++it) {
            int l = tid + it * 256;
            int k = l >> 5;
            int nn = (l & 31) << 2;
            *(f4*)&Bs[k][nn] = *(const f4*)(w + (size_t)(d0 + k) * EMBED + n0 + nn);
        }
        __syncthreads();
#pragma unroll
        for (int k = 0; k < 16; ++k) {
            float a[8], b[8];
            *(f4*)&a[0] = *(f4*)&As[k][ty * 8];
            *(f4*)&a[4] = *(f4*)&As[k][ty * 8 + 4];
            *(f4*)&b[0] = *(f4*)&Bs[k][tx * 4];
            *(f4*)&b[4] = *(f4*)&Bs[k][64 + tx * 4];
#pragma unroll
            for (int i = 0; i < 8; ++i)
#pragma unroll
                for (int j = 0; j < 8; ++j)
                    acc[i][j] = fmaf(a[i], b[j], acc[i][j]);
        }
    }
#pragma unroll
    for (int i = 0; i < 8; ++i) {
        int row = row0 + ty * 8 + i;
#pragma unroll
        for (int g = 0; g < 2; ++g) {
            int n = n0 + g * 64 + tx * 4;
            f4 o;
            o.x = acc[i][g * 4 + 0];
            o.y = acc[i][g * 4 + 1];
            o.z = acc[i][g * 4 + 2];
            o.w = acc[i][g * 4 + 3];
            *(f4*)(out + (size_t)row * EMBED + n) = o;
        }
    }
}

// ------------------------------------------------------------------
extern "C" void kernel_launch(void* const* d_in, const int* in_sizes, int n_in,
                              void* d_out, int out_size, void* d_ws, size_t ws_size,
                              hipStream_t stream) {
    const float* x  = (const float*)d_in[0];
    const float* wq = (const float*)d_in[1];
    const float* wk = (const float*)d_in[2];
    const float* wv = (const float*)d_in[3];
    const float* w  = (const float*)d_in[4];
    float* out = (float*)d_out;

    u16* Qhi = (u16*)d_ws;
    u16* Qlo = Qhi + NTOK;
    u16* Khi = Qlo + NTOK;
    u16* Klo = Khi + NTOK;
    u16* Vt  = Klo + NTOK;
    float* heads = (float*)(Vt + NTOK);     // 5*16.78MB offset, 16B aligned

    dim3 g1(64, 24);   // 8192/128 x 3072/128
    qkv_proj_kernel<<<g1, 256, 0, stream>>>(x, wq, wk, wv, Qhi, Qlo, Khi, Klo, Vt);

    dim3 g2(SEQ / 128, BH);   // 16 x 64
    attn_kernel<<<g2, 256, 0, stream>>>(Qhi, Qlo, Khi, Klo, Vt, heads);

    dim3 g3(64, 8);    // 8192/128 x 1024/128
    out_proj_kernel<<<g3, 256, 0, stream>>>(heads, w, out);
}

// Round 3
// 550.250 us; speedup vs baseline: 3.5724x; 2.0278x over previous
//
#include <hip/hip_runtime.h>
#include <hip/hip_bf16.h>
#include <math.h>

#define EMBED 1024
#define KD 64
#define NH 16
#define SEQ 2048
#define BATCH 4
#define BH (BATCH * NH)     // 64
#define NTOK ((size_t)BH * SEQ * KD)   // 8,388,608

typedef float4 f4;
typedef unsigned short u16;
typedef __attribute__((ext_vector_type(8))) short v8s;   // 8 bf16 (MFMA A/B frag)
typedef __attribute__((ext_vector_type(4))) float v4f;   // MFMA C/D frag

__device__ __forceinline__ u16 f2bf(float f) {
    unsigned u = __float_as_uint(f);
    unsigned r = (u + 0x7fffu + ((u >> 16) & 1u)) >> 16;
    return (u16)r;
}
__device__ __forceinline__ float bf2f(u16 h) {
    return __uint_as_float(((unsigned)h) << 16);
}

// async global->LDS, 16B/lane. LDS dest = wave-uniform base + lane*16.
__device__ __forceinline__ void gload_lds16(const void* g, void* l) {
    __builtin_amdgcn_global_load_lds(
        (const __attribute__((address_space(1))) unsigned int*)g,
        (__attribute__((address_space(3))) unsigned int*)l, 16, 0, 0);
}

// ------------------------------------------------------------------
// Converter 1: x fp32 -> xh/xl bf16 (hi/lo split), [8192][1024]
// ------------------------------------------------------------------
__global__ __launch_bounds__(256)
void convert_x_kernel(const float* __restrict__ x,
                      u16* __restrict__ xh, u16* __restrict__ xl)
{
    size_t i = ((size_t)blockIdx.x * 256 + threadIdx.x) * 4;
    f4 v = *(const f4*)(x + i);
    u16 h0 = f2bf(v.x), h1 = f2bf(v.y), h2 = f2bf(v.z), h3 = f2bf(v.w);
    u16 l0 = f2bf(v.x - bf2f(h0)), l1 = f2bf(v.y - bf2f(h1));
    u16 l2 = f2bf(v.z - bf2f(h2)), l3 = f2bf(v.w - bf2f(h3));
    uint2 H, L;
    H.x = (unsigned)h0 | ((unsigned)h1 << 16);
    H.y = (unsigned)h2 | ((unsigned)h3 << 16);
    L.x = (unsigned)l0 | ((unsigned)l1 << 16);
    L.y = (unsigned)l2 | ((unsigned)l3 << 16);
    *(uint2*)(xh + i) = H;
    *(uint2*)(xl + i) = L;
}

// ------------------------------------------------------------------
// Converter 2: wq/wk/wv [H][D][64] fp32 -> Wt hi/lo [3072][1024] bf16
// (transposed: row n = mat*1024 + h*64 + c, col = d). Q scaled by 0.125.
// ------------------------------------------------------------------
__global__ __launch_bounds__(256)
void convert_w_kernel(const float* __restrict__ wq, const float* __restrict__ wk,
                      const float* __restrict__ wv,
                      u16* __restrict__ Wth, u16* __restrict__ Wtl)
{
    int n = blockIdx.x;                       // 0..3071
    int mat = n >> 10, nin = n & 1023, h = nin >> 6, c = nin & 63;
    const float* __restrict__ ws = (mat == 0) ? wq : (mat == 1) ? wk : wv;
    float sc = (mat == 0) ? 0.125f : 1.0f;
    for (int d = threadIdx.x; d < EMBED; d += 256) {
        float f = ws[((size_t)h * EMBED + d) * KD + c] * sc;
        u16 hi = f2bf(f);
        u16 lo = f2bf(f - bf2f(hi));
        Wth[(size_t)n * EMBED + d] = hi;
        Wtl[(size_t)n * EMBED + d] = lo;
    }
}

// ------------------------------------------------------------------
// Converter 3: w [1024][1024] fp32 -> OWt hi/lo [n][k] bf16 (transposed)
// ------------------------------------------------------------------
__global__ __launch_bounds__(256)
void convert_ow_kernel(const float* __restrict__ w,
                       u16* __restrict__ OWth, u16* __restrict__ OWtl)
{
    int n = blockIdx.x;                       // 0..1023
    for (int k = threadIdx.x; k < EMBED; k += 256) {
        float f = w[(size_t)k * EMBED + n];
        u16 hi = f2bf(f);
        u16 lo = f2bf(f - bf2f(hi));
        OWth[(size_t)n * EMBED + k] = hi;
        OWtl[(size_t)n * EMBED + k] = lo;
    }
}

// ------------------------------------------------------------------
// Kernel: QKV projection, MFMA bf16. 128x128 tile, BK=64, 4 waves (2x2,
// 64x64 each). 3-term split for Q/K tiles (n0<2048), 1-term for V.
// LDS rows are 128B with 16B-block XOR swizzle blk^(row&7), baked into
// the per-lane global_load_lds source address -> conflict-free frag reads.
// Epilogue writes the attention-kernel layouts (Q plain, K cc-swizzled,
// Vt transposed + key-block swizzled).
// ------------------------------------------------------------------
__global__ __launch_bounds__(256)
void qkv_mfma_kernel(const u16* __restrict__ xh, const u16* __restrict__ xl,
                     const u16* __restrict__ Wth, const u16* __restrict__ Wtl,
                     u16* __restrict__ Qhi, u16* __restrict__ Qlo,
                     u16* __restrict__ Khi, u16* __restrict__ Klo,
                     u16* __restrict__ Vt)
{
    __shared__ u16 sAh[128 * 64];
    __shared__ u16 sAl[128 * 64];
    __shared__ u16 sBh[128 * 64];
    __shared__ u16 sBl[128 * 64];
    const int tid = threadIdx.x;
    const int lane = tid & 63, wid = tid >> 6;
    const int lm = lane & 15, lq = lane >> 4;
    const int wm = wid & 1, wn = wid >> 1;
    const int m0 = blockIdx.y * 128;
    const int n0 = blockIdx.x * 128;          // 0..2944
    const bool three = (n0 < 2048);

    v4f acc[4][4];
#pragma unroll
    for (int mt = 0; mt < 4; ++mt)
#pragma unroll
        for (int nt = 0; nt < 4; ++nt)
            acc[mt][nt] = (v4f){0.f, 0.f, 0.f, 0.f};

    const int srow = wid * 32 + (lane >> 3);       // staging row (i*8 added)
    const int sblk = (lane & 7) ^ (lane >> 3);     // swizzled 16B-block

    for (int k0 = 0; k0 < EMBED; k0 += 64) {
        __syncthreads();
#pragma unroll
        for (int i = 0; i < 4; ++i) {
            int row = srow + i * 8;
            size_t gA = (((size_t)(m0 + row)) << 10) + k0 + sblk * 8;
            size_t gB = (((size_t)(n0 + row)) << 10) + k0 + sblk * 8;
            int lo = (wid * 32 + i * 8) * 128;     // LDS byte offset
            gload_lds16((const char*)xh + gA * 2, (char*)sAh + lo);
            gload_lds16((const char*)Wth + gB * 2, (char*)sBh + lo);
            if (three) {
                gload_lds16((const char*)xl + gA * 2, (char*)sAl + lo);
                gload_lds16((const char*)Wtl + gB * 2, (char*)sBl + lo);
            }
        }
        asm volatile("s_waitcnt vmcnt(0)" ::: "memory");
        __syncthreads();

#pragma unroll
        for (int kks = 0; kks < 2; ++kks) {
            v8s ah[4], bh[4];
            const int ba = ((kks * 4 + lq) ^ (lm & 7)) * 8;
#pragma unroll
            for (int t = 0; t < 4; ++t) {
                int ra = wm * 64 + t * 16 + lm;
                int rb = wn * 64 + t * 16 + lm;
                ah[t] = *(const v8s*)&sAh[ra * 64 + ba];
                bh[t] = *(const v8s*)&sBh[rb * 64 + ba];
            }
            if (three) {
                v8s al[4], bl[4];
#pragma unroll
                for (int t = 0; t < 4; ++t) {
                    int ra = wm * 64 + t * 16 + lm;
                    int rb = wn * 64 + t * 16 + lm;
                    al[t] = *(const v8s*)&sAl[ra * 64 + ba];
                    bl[t] = *(const v8s*)&sBl[rb * 64 + ba];
                }
#pragma unroll
                for (int mt = 0; mt < 4; ++mt)
#pragma unroll
                    for (int nt = 0; nt < 4; ++nt) {
                        acc[mt][nt] = __builtin_amdgcn_mfma_f32_16x16x32_bf16(ah[mt], bh[nt], acc[mt][nt], 0, 0, 0);
                        acc[mt][nt] = __builtin_amdgcn_mfma_f32_16x16x32_bf16(ah[mt], bl[nt], acc[mt][nt], 0, 0, 0);
                        acc[mt][nt] = __builtin_amdgcn_mfma_f32_16x16x32_bf16(al[mt], bh[nt], acc[mt][nt], 0, 0, 0);
                    }
            } else {
#pragma unroll
                for (int mt = 0; mt < 4; ++mt)
#pragma unroll
                    for (int nt = 0; nt < 4; ++nt)
                        acc[mt][nt] = __builtin_amdgcn_mfma_f32_16x16x32_bf16(ah[mt], bh[nt], acc[mt][nt], 0, 0, 0);
            }
        }
    }

    // ---- epilogue: C row(m) = mt*16+lq*4+r, col(n) = nt*16+lm
    const int mrow0 = m0 + wm * 64;
    const int ncol0 = n0 + wn * 64;
    if (!three) {
        // V tiles -> Vt[bh][hd][key-swizzled], uint2-packed (4 consecutive s)
#pragma unroll
        for (int mt = 0; mt < 4; ++mt) {
            int sbase = mrow0 + mt * 16 + lq * 4;
            int bb = sbase >> 11, s = sbase & 2047;
#pragma unroll
            for (int nt = 0; nt < 4; ++nt) {
                int nin = (ncol0 + nt * 16 + lm) & 1023;
                int h = nin >> 6, cc = nin & 63;
                int bh_ = bb * NH + h;
                size_t a = ((size_t)bh_ * KD + cc) * SEQ
                         + (size_t)(((((s >> 3) ^ (cc & 7)) << 3)) | (s & 7));
                uint2 u;
                u.x = (unsigned)f2bf(acc[mt][nt][0]) | ((unsigned)f2bf(acc[mt][nt][1]) << 16);
                u.y = (unsigned)f2bf(acc[mt][nt][2]) | ((unsigned)f2bf(acc[mt][nt][3]) << 16);
                *(uint2*)(Vt + a) = u;
            }
        }
    } else {
        const bool isQ = (n0 < 1024);
#pragma unroll
        for (int mt = 0; mt < 4; ++mt) {
            int sbase = mrow0 + mt * 16 + lq * 4;
            int bb = sbase >> 11, sB = sbase & 2047;
#pragma unroll
            for (int nt = 0; nt < 4; ++nt) {
                int nin = (ncol0 + nt * 16 + lm) & 1023;
                int h = nin >> 6, cc = nin & 63;
                int bh_ = bb * NH + h;
#pragma unroll
                for (int r = 0; r < 4; ++r) {
                    int s = sB + r;
                    float f = acc[mt][nt][r];
                    u16 hi = f2bf(f);
                    u16 lo = f2bf(f - bf2f(hi));
                    if (isQ) {
                        size_t a = ((size_t)bh_ * SEQ + s) * KD + cc;
                        Qhi[a] = hi;
                        Qlo[a] = lo;
                    } else {
                        int ccp = ((((cc >> 3) ^ (s & 7)) << 3) | (cc & 7));
                        size_t a = ((size_t)bh_ * SEQ + s) * KD + ccp;
                        Khi[a] = hi;
                        Klo[a] = lo;
                    }
                }
            }
        }
    }
}

// ------------------------------------------------------------------
// Kernel: flash attention, MFMA bf16 (unchanged from R2 except heads
// is now written as bf16 for the out-projection).
// ------------------------------------------------------------------
#define PSTRIDE 88

__global__ __launch_bounds__(256)
void attn_kernel(const u16* __restrict__ Qhi, const u16* __restrict__ Qlo,
                 const u16* __restrict__ Khi, const u16* __restrict__ Klo,
                 const u16* __restrict__ Vt,  u16* __restrict__ headsb)
{
    __shared__ u16 sKhi[64 * 64];
    __shared__ u16 sKlo[64 * 64];
    __shared__ u16 sVt[64 * 64];
    __shared__ u16 sPs[128 * PSTRIDE];

    const int tid = threadIdx.x;
    const int lane = tid & 63, wid = tid >> 6;
    const int lm = lane & 15, lq = lane >> 4;
    const int q0 = blockIdx.x * 128;
    const int bh = blockIdx.y;
    const int bb = bh >> 4, h = bh & 15;

    v8s qh[2][2], ql[2][2];
#pragma unroll
    for (int mt = 0; mt < 2; ++mt)
#pragma unroll
        for (int kk = 0; kk < 2; ++kk) {
            size_t g = ((size_t)bh * SEQ + q0 + wid * 32 + mt * 16 + lm) * KD
                     + kk * 32 + lq * 8;
            qh[mt][kk] = *(const v8s*)(Qhi + g);
            ql[mt][kk] = *(const v8s*)(Qlo + g);
        }

    v4f ctx[2][4];
    float mrun[2][4], lrun[2][4];
#pragma unroll
    for (int mt = 0; mt < 2; ++mt)
#pragma unroll
        for (int r = 0; r < 4; ++r) {
            mrun[mt][r] = -INFINITY;
            lrun[mt][r] = 0.f;
        }
#pragma unroll
    for (int mt = 0; mt < 2; ++mt)
#pragma unroll
        for (int nt = 0; nt < 4; ++nt)
            ctx[mt][nt] = (v4f){0.f, 0.f, 0.f, 0.f};

    const size_t kbase = (size_t)bh * SEQ * KD;

    for (int t0 = 0; t0 < SEQ; t0 += 64) {
        __syncthreads();
        {
            const char* gk1 = (const char*)(Khi + kbase + (size_t)t0 * KD);
            const char* gk2 = (const char*)(Klo + kbase + (size_t)t0 * KD);
            char* l1 = (char*)sKhi;
            char* l2 = (char*)sKlo;
            int off = wid * 2048;
#pragma unroll
            for (int i = 0; i < 2; ++i) {
                int o = off + i * 1024;
                gload_lds16(gk1 + o + lane * 16, l1 + o);
                gload_lds16(gk2 + o + lane * 16, l2 + o);
            }
        }
#pragma unroll
        for (int it = 0; it < 2; ++it) {
            int slot = it * 256 + tid;
            int row = slot >> 3, seg = slot & 7;
            uint4 v = *(const uint4*)(Vt + ((size_t)(bh * KD + row)) * SEQ + t0 + seg * 8);
            *(uint4*)&sVt[row * 64 + seg * 8] = v;
        }
        asm volatile("s_waitcnt vmcnt(0)" ::: "memory");
        __syncthreads();

        v4f sc[2][4];
#pragma unroll
        for (int mt = 0; mt < 2; ++mt)
#pragma unroll
            for (int nt = 0; nt < 4; ++nt)
                sc[mt][nt] = (v4f){0.f, 0.f, 0.f, 0.f};
#pragma unroll
        for (int kk = 0; kk < 2; ++kk) {
#pragma unroll
            for (int nt = 0; nt < 4; ++nt) {
                int key = nt * 16 + lm;
                int blk = (kk * 4 + lq) ^ (key & 7);
                v8s bh16 = *(const v8s*)&sKhi[key * 64 + blk * 8];
                v8s bl16 = *(const v8s*)&sKlo[key * 64 + blk * 8];
#pragma unroll
                for (int mt = 0; mt < 2; ++mt) {
                    sc[mt][nt] = __builtin_amdgcn_mfma_f32_16x16x32_bf16(qh[mt][kk], bh16, sc[mt][nt], 0, 0, 0);
                    sc[mt][nt] = __builtin_amdgcn_mfma_f32_16x16x32_bf16(qh[mt][kk], bl16, sc[mt][nt], 0, 0, 0);
                    sc[mt][nt] = __builtin_amdgcn_mfma_f32_16x16x32_bf16(ql[mt][kk], bh16, sc[mt][nt], 0, 0, 0);
                }
            }
        }

#pragma unroll
        for (int mt = 0; mt < 2; ++mt) {
#pragma unroll
            for (int r = 0; r < 4; ++r) {
                float v0 = sc[mt][0][r], v1 = sc[mt][1][r];
                float v2 = sc[mt][2][r], v3 = sc[mt][3][r];
                float mx = fmaxf(fmaxf(v0, v1), fmaxf(v2, v3));
                mx = fmaxf(mx, __shfl_xor(mx, 1));
                mx = fmaxf(mx, __shfl_xor(mx, 2));
                mx = fmaxf(mx, __shfl_xor(mx, 4));
                mx = fmaxf(mx, __shfl_xor(mx, 8));
                float mnew = fmaxf(mrun[mt][r], mx);
                float alpha = __expf(mrun[mt][r] - mnew);
                float p0 = __expf(v0 - mnew), p1 = __expf(v1 - mnew);
                float p2 = __expf(v2 - mnew), p3 = __expf(v3 - mnew);
                float rs = p0 + p1 + p2 + p3;
                rs += __shfl_xor(rs, 1);
                rs += __shfl_xor(rs, 2);
                rs += __shfl_xor(rs, 4);
                rs += __shfl_xor(rs, 8);
                mrun[mt][r] = mnew;
                lrun[mt][r] = lrun[mt][r] * alpha + rs;
#pragma unroll
                for (int nt = 0; nt < 4; ++nt)
                    ctx[mt][nt][r] *= alpha;
                int row = wid * 32 + mt * 16 + lq * 4 + r;
                sPs[row * PSTRIDE +  0 + lm] = f2bf(p0);
                sPs[row * PSTRIDE + 16 + lm] = f2bf(p1);
                sPs[row * PSTRIDE + 32 + lm] = f2bf(p2);
                sPs[row * PSTRIDE + 48 + lm] = f2bf(p3);
            }
        }

#pragma unroll
        for (int kk2 = 0; kk2 < 2; ++kk2) {
            v8s a[2];
#pragma unroll
            for (int mt = 0; mt < 2; ++mt)
                a[mt] = *(const v8s*)&sPs[(wid * 32 + mt * 16 + lm) * PSTRIDE + kk2 * 32 + lq * 8];
#pragma unroll
            for (int nt = 0; nt < 4; ++nt) {
                int hd = nt * 16 + lm;
                int blk = (kk2 * 4 + lq) ^ (hd & 7);
                v8s b = *(const v8s*)&sVt[hd * 64 + blk * 8];
#pragma unroll
                for (int mt = 0; mt < 2; ++mt)
                    ctx[mt][nt] = __builtin_amdgcn_mfma_f32_16x16x32_bf16(a[mt], b, ctx[mt][nt], 0, 0, 0);
            }
        }
    }

#pragma unroll
    for (int mt = 0; mt < 2; ++mt)
#pragma unroll
        for (int r = 0; r < 4; ++r) {
            int row = q0 + wid * 32 + mt * 16 + lq * 4 + r;
            float inv = 1.0f / lrun[mt][r];
            u16* dst = headsb + ((size_t)bb * SEQ + row) * EMBED + h * KD;
#pragma unroll
            for (int nt = 0; nt < 4; ++nt)
                dst[nt * 16 + lm] = f2bf(ctx[mt][nt][r] * inv);
        }
}

// ------------------------------------------------------------------
// Kernel: output projection, MFMA bf16 2-term (Ah*Bh + Ah*Bl).
// out[8192,1024] fp32 = heads(bf16) @ w(split bf16, transposed [n][k]).
// ------------------------------------------------------------------
__global__ __launch_bounds__(256)
void out_mfma_kernel(const u16* __restrict__ headsb,
                     const u16* __restrict__ OWth, const u16* __restrict__ OWtl,
                     float* __restrict__ out)
{
    __shared__ u16 sA[128 * 64];
    __shared__ u16 sBh[128 * 64];
    __shared__ u16 sBl[128 * 64];
    const int tid = threadIdx.x;
    const int lane = tid & 63, wid = tid >> 6;
    const int lm = lane & 15, lq = lane >> 4;
    const int wm = wid & 1, wn = wid >> 1;
    const int m0 = blockIdx.y * 128;
    const int n0 = blockIdx.x * 128;

    v4f acc[4][4];
#pragma unroll
    for (int mt = 0; mt < 4; ++mt)
#pragma unroll
        for (int nt = 0; nt < 4; ++nt)
            acc[mt][nt] = (v4f){0.f, 0.f, 0.f, 0.f};

    const int srow = wid * 32 + (lane >> 3);
    const int sblk = (lane & 7) ^ (lane >> 3);

    for (int k0 = 0; k0 < EMBED; k0 += 64) {
        __syncthreads();
#pragma unroll
        for (int i = 0; i < 4; ++i) {
            int row = srow + i * 8;
            size_t gA = (((size_t)(m0 + row)) << 10) + k0 + sblk * 8;
            size_t gB = (((size_t)(n0 + row)) << 10) + k0 + sblk * 8;
            int lo = (wid * 32 + i * 8) * 128;
            gload_lds16((const char*)headsb + gA * 2, (char*)sA + lo);
            gload_lds16((const char*)OWth + gB * 2, (char*)sBh + lo);
            gload_lds16((const char*)OWtl + gB * 2, (char*)sBl + lo);
        }
        asm volatile("s_waitcnt vmcnt(0)" ::: "memory");
        __syncthreads();

#pragma unroll
        for (int kks = 0; kks < 2; ++kks) {
            const int ba = ((kks * 4 + lq) ^ (lm & 7)) * 8;
            v8s ah[4], bh[4], bl[4];
#pragma unroll
            for (int t = 0; t < 4; ++t) {
                int ra = wm * 64 + t * 16 + lm;
                int rb = wn * 64 + t * 16 + lm;
                ah[t] = *(const v8s*)&sA[ra * 64 + ba];
                bh[t] = *(const v8s*)&sBh[rb * 64 + ba];
                bl[t] = *(const v8s*)&sBl[rb * 64 + ba];
            }
#pragma unroll
            for (int mt = 0; mt < 4; ++mt)
#pragma unroll
                for (int nt = 0; nt < 4; ++nt) {
                    acc[mt][nt] = __builtin_amdgcn_mfma_f32_16x16x32_bf16(ah[mt], bh[nt], acc[mt][nt], 0, 0, 0);
                    acc[mt][nt] = __builtin_amdgcn_mfma_f32_16x16x32_bf16(ah[mt], bl[nt], acc[mt][nt], 0, 0, 0);
                }
        }
    }

    const int mrow0 = m0 + wm * 64;
    const int ncol0 = n0 + wn * 64;
#pragma unroll
    for (int mt = 0; mt < 4; ++mt) {
        int sbase = mrow0 + mt * 16 + lq * 4;
#pragma unroll
        for (int nt = 0; nt < 4; ++nt) {
            int n = ncol0 + nt * 16 + lm;
#pragma unroll
            for (int r = 0; r < 4; ++r)
                out[(size_t)(sbase + r) * EMBED + n] = acc[mt][nt][r];
        }
    }
}

// ------------------------------------------------------------------
extern "C" void kernel_launch(void* const* d_in, const int* in_sizes, int n_in,
                              void* d_out, int out_size, void* d_ws, size_t ws_size,
                              hipStream_t stream) {
    const float* x  = (const float*)d_in[0];
    const float* wq = (const float*)d_in[1];
    const float* wk = (const float*)d_in[2];
    const float* wv = (const float*)d_in[3];
    const float* w  = (const float*)d_in[4];
    float* out = (float*)d_out;

    u16* Qhi = (u16*)d_ws;
    u16* Qlo = Qhi + NTOK;
    u16* Khi = Qlo + NTOK;
    u16* Klo = Khi + NTOK;
    u16* Vt  = Klo + NTOK;
    u16* xh  = Vt + NTOK;                 // [8192][1024]
    u16* xl  = xh + NTOK;
    u16* Wth = xl + NTOK;                 // [3072][1024]
    u16* Wtl = Wth + (size_t)3072 * 1024;
    u16* OWth = Wtl + (size_t)3072 * 1024;  // [1024][1024]
    u16* OWtl = OWth + (size_t)1024 * 1024;
    u16* headsb = xh;                     // alias: xh dead after qkv_mfma
    // total = 128 MiB exactly (same as R1 footprint)

    convert_x_kernel<<<8192, 256, 0, stream>>>(x, xh, xl);
    convert_w_kernel<<<3072, 256, 0, stream>>>(wq, wk, wv, Wth, Wtl);
    convert_ow_kernel<<<1024, 256, 0, stream>>>(w, OWth, OWtl);

    dim3 g1(24, 64);   // n-tiles x m-tiles
    qkv_mfma_kernel<<<g1, 256, 0, stream>>>(xh, xl, Wth, Wtl, Qhi, Qlo, Khi, Klo, Vt);

    dim3 g2(SEQ / 128, BH);   // 16 x 64
    attn_kernel<<<g2, 256, 0, stream>>>(Qhi, Qlo, Khi, Klo, Vt, headsb);

    dim3 g3(8, 64);
    out_mfma_kernel<<<g3, 256, 0, stream>>>(headsb, OWth, OWtl, out);
}